// Round 5
// baseline (911.390 us; speedup 1.0000x reference)
//
#include <hip/hip_runtime.h>

#define IN_DIM 384
#define HID    128

#define AS1 __attribute__((address_space(1)))
#define AS3 __attribute__((address_space(3)))

typedef _Float16 half8 __attribute__((ext_vector_type(8)));
typedef _Float16 half2t __attribute__((ext_vector_type(2)));
typedef __fp16 fp16x2 __attribute__((ext_vector_type(2)));
typedef float floatx4 __attribute__((ext_vector_type(4)));

// ---------------- utility ----------------
__global__ void zero_i32(int* __restrict__ p, int n) {
  int i = blockIdx.x * 256 + threadIdx.x;
  if (i < n) p[i] = 0;
}

// ---------------- direct exact-CSR build ----------------
// 1) hist: cnt[d] = degree (global atomics; 400KB counter array is L2-resident)
__global__ __launch_bounds__(256) void hist_kernel(
    const int* __restrict__ dst, int E, int* __restrict__ cnt) {
  for (int i = blockIdx.x * 256 + threadIdx.x; i < E; i += gridDim.x * 256)
    atomicAdd(&cnt[dst[i]], 1);
}

// 2a) per-256-block exclusive scan; block sums -> bsum
__global__ __launch_bounds__(256) void scan_block(
    const int* __restrict__ cnt, int N, int* __restrict__ rs, int* __restrict__ bsum) {
  __shared__ int s[256];
  const int t = threadIdx.x;
  const int node = blockIdx.x * 256 + t;
  int v = (node < N) ? cnt[node] : 0;
  s[t] = v;
  __syncthreads();
  for (int off = 1; off < 256; off <<= 1) {
    int y = (t >= off) ? s[t - off] : 0;
    __syncthreads();
    s[t] += y;
    __syncthreads();
  }
  if (node < N) rs[node] = s[t] - v;          // exclusive within block
  if (t == 255) bsum[blockIdx.x] = s[255];    // block total
}

// 2b) scan the 391 block sums (single block)
__global__ __launch_bounds__(512) void scan_top(int* __restrict__ bsum, int nBlk) {
  __shared__ int s[512];
  const int t = threadIdx.x;
  int v = (t < nBlk) ? bsum[t] : 0;
  s[t] = v;
  __syncthreads();
  for (int off = 1; off < 512; off <<= 1) {
    int y = (t >= off) ? s[t - off] : 0;
    __syncthreads();
    s[t] += y;
    __syncthreads();
  }
  if (t < nBlk) bsum[t] = s[t] - v;           // exclusive
}

// 2c) add block offsets; emit rs / re / cur
__global__ __launch_bounds__(256) void scan_add(
    const int* __restrict__ cnt, const int* __restrict__ bsum, int N,
    int* __restrict__ rs, int* __restrict__ re, int* __restrict__ cur) {
  const int node = blockIdx.x * 256 + threadIdx.x;
  if (node < N) {
    int r = rs[node] + bsum[blockIdx.x];
    rs[node] = r;
    cur[node] = r;
    re[node] = r + cnt[node];
  }
}

// 3) scatter edges into exact CSR slots
__global__ __launch_bounds__(256) void scatter_kernel(
    const int* __restrict__ src, const int* __restrict__ dst, int E,
    int* __restrict__ cur, int* __restrict__ sorted_src) {
  for (int i = blockIdx.x * 256 + threadIdx.x; i < E; i += gridDim.x * 256) {
    int d = dst[i];
    int p = atomicAdd(&cur[d], 1);
    sorted_src[p] = src[i];
  }
}

// ---------------- weight pack: W[K][128] fp32 -> per-lane MFMA B-fragment order ------
// grid (8, KS, 2): z=0 -> Wl (tn 0..7), z=1 -> Wr (tn 8..15)
__global__ void pack_w2(const float* __restrict__ Wl, const float* __restrict__ Wr,
                        _Float16* __restrict__ Bp) {
  const float* __restrict__ W = blockIdx.z ? Wr : Wl;
  const int tn = blockIdx.x;
  const int ks = blockIdx.y;
  const int KS = gridDim.y;
  const int lane = threadIdx.x;
  const int n = tn * 16 + (lane & 15);
  const int kb = ks * 32 + (lane >> 4) * 8;
  half8 v;
#pragma unroll
  for (int j = 0; j < 8; ++j) v[j] = (_Float16)W[(size_t)(kb + j) * HID + n];
  *(half8*)(Bp + (((size_t)(blockIdx.z * 8 + tn) * KS + ks) * 64 + lane) * 8) = v;
}

// ---------------- cvt helper: pack two fp32 -> fp16x2 (RTZ), as half2t --------------
__device__ inline half2t cvt_pk(float a, float b) {
  fp16x2 r = __builtin_amdgcn_cvt_pkrtz(a, b);
  union { fp16x2 f; half2t h; } c;
  c.f = r;
  return c.h;
}

// ---------------- GEMM (fp32 A): C[M x 256] = A[M x K] @ [Bl | Br], K = IN_DIM -------
__global__ __launch_bounds__(512) void gemm_f32a(
    const float* __restrict__ A, int M,
    const _Float16* __restrict__ Bp, _Float16* __restrict__ C) {
  __shared__ float As[128 * 32];   // (row*8 + cg_phys)*4 floats, cg_phys = cg ^ (row&7)

  const int K = IN_DIM, KS = IN_DIM / 32;
  const int tid = threadIdx.x;
  const int lane = tid & 63;
  const int wid = tid >> 6;
  const int quad = lane >> 4;
  const int lm = lane & 15;
  const int row0 = (wid & 1) * 64;
  const int ct0 = (wid >> 1) * 4;
  const int blockRow = blockIdx.x * 128;

  const int srow = lane >> 3;
  const int scol = ((lane & 7) ^ (srow & 7)) * 4;
  const int grow0 = min(blockRow + wid * 16 + srow, M - 1);
  const int grow1 = min(blockRow + wid * 16 + 8 + srow, M - 1);

  floatx4 acc[16];
#pragma unroll
  for (int i = 0; i < 16; ++i) {
    acc[i][0] = 0.f; acc[i][1] = 0.f; acc[i][2] = 0.f; acc[i][3] = 0.f;
  }

  for (int ks = 0; ks < KS; ++ks) {
    const int k0 = ks * 32;
    __syncthreads();
    __builtin_amdgcn_global_load_lds(
        (const AS1 void*)(A + (size_t)grow0 * K + k0 + scol),
        (AS3 void*)(As + (wid * 16) * 32), 16, 0, 0);
    __builtin_amdgcn_global_load_lds(
        (const AS1 void*)(A + (size_t)grow1 * K + k0 + scol),
        (AS3 void*)(As + (wid * 16 + 8) * 32), 16, 0, 0);

    half8 bf[4];
#pragma unroll
    for (int ct = 0; ct < 4; ++ct)
      bf[ct] = *(const half8*)(Bp + (((size_t)(ct0 + ct) * KS + ks) * 64 + lane) * 8);

    __syncthreads();

    half8 af[4];
#pragma unroll
    for (int rt = 0; rt < 4; ++rt) {
      const int row = row0 + rt * 16 + lm;
      const int sw = row & 7;
      const floatx4 fA = *(const floatx4*)&As[(row * 8 + ((quad * 2) ^ sw)) * 4];
      const floatx4 fB = *(const floatx4*)&As[(row * 8 + ((quad * 2 + 1) ^ sw)) * 4];
      half2t h01 = cvt_pk(fA[0], fA[1]);
      half2t h23 = cvt_pk(fA[2], fA[3]);
      half2t h45 = cvt_pk(fB[0], fB[1]);
      half2t h67 = cvt_pk(fB[2], fB[3]);
      half8 a;
      a[0] = h01[0]; a[1] = h01[1]; a[2] = h23[0]; a[3] = h23[1];
      a[4] = h45[0]; a[5] = h45[1]; a[6] = h67[0]; a[7] = h67[1];
      af[rt] = a;
    }
#pragma unroll
    for (int rt = 0; rt < 4; ++rt)
#pragma unroll
      for (int ct = 0; ct < 4; ++ct)
        acc[rt * 4 + ct] =
            __builtin_amdgcn_mfma_f32_16x16x32_f16(af[rt], bf[ct], acc[rt * 4 + ct], 0, 0, 0);
  }

#pragma unroll
  for (int rt = 0; rt < 4; ++rt) {
#pragma unroll
    for (int r = 0; r < 4; ++r) {
      const int gm = blockRow + row0 + rt * 16 + quad * 4 + r;
      if (gm < M) {
#pragma unroll
        for (int ct = 0; ct < 4; ++ct)
          C[(size_t)gm * 256 + (ct0 + ct) * 16 + lm] = (_Float16)acc[rt * 4 + ct][r];
      }
    }
  }
}

// ---------------- GEMM (fp16 A): C[M x 256] = A[M x 128] @ [Bl | Br] ----------------
__global__ __launch_bounds__(512) void gemm_f16a(
    const _Float16* __restrict__ A, int M,
    const _Float16* __restrict__ Bp, _Float16* __restrict__ C) {
  __shared__ _Float16 As[128 * 32];  // (row*4 + cg_phys)*8 halfs

  const int K = HID, KS = HID / 32;
  const int tid = threadIdx.x;
  const int lane = tid & 63;
  const int wid = tid >> 6;
  const int quad = lane >> 4;
  const int lm = lane & 15;
  const int row0 = (wid & 1) * 64;
  const int ct0 = (wid >> 1) * 4;
  const int blockRow = blockIdx.x * 128;

  const int srow = lane >> 2;
  const int scol = ((lane & 3) ^ ((lane >> 3) & 3)) * 8;
  const int grow = min(blockRow + wid * 16 + srow, M - 1);

  floatx4 acc[16];
#pragma unroll
  for (int i = 0; i < 16; ++i) {
    acc[i][0] = 0.f; acc[i][1] = 0.f; acc[i][2] = 0.f; acc[i][3] = 0.f;
  }

  for (int ks = 0; ks < KS; ++ks) {
    const int k0 = ks * 32;
    __syncthreads();
    __builtin_amdgcn_global_load_lds(
        (const AS1 void*)(A + (size_t)grow * K + k0 + scol),
        (AS3 void*)(As + (wid * 16) * 32), 16, 0, 0);

    half8 bf[4];
#pragma unroll
    for (int ct = 0; ct < 4; ++ct)
      bf[ct] = *(const half8*)(Bp + (((size_t)(ct0 + ct) * KS + ks) * 64 + lane) * 8);

    __syncthreads();

    half8 af[4];
#pragma unroll
    for (int rt = 0; rt < 4; ++rt) {
      const int row = row0 + rt * 16 + lm;
      const int cg = quad ^ ((row >> 1) & 3);
      af[rt] = *(const half8*)&As[(row * 4 + cg) * 8];
    }
#pragma unroll
    for (int rt = 0; rt < 4; ++rt)
#pragma unroll
      for (int ct = 0; ct < 4; ++ct)
        acc[rt * 4 + ct] =
            __builtin_amdgcn_mfma_f32_16x16x32_f16(af[rt], bf[ct], acc[rt * 4 + ct], 0, 0, 0);
  }

#pragma unroll
  for (int rt = 0; rt < 4; ++rt) {
#pragma unroll
    for (int r = 0; r < 4; ++r) {
      const int gm = blockRow + row0 + rt * 16 + quad * 4 + r;
      if (gm < M) {
#pragma unroll
        for (int ct = 0; ct < 4; ++ct)
          C[(size_t)gm * 256 + (ct0 + ct) * 16 + lm] = (_Float16)acc[rt * 4 + ct][r];
      }
    }
  }
}

// ---------------- helpers ----------------
__device__ inline float2 upk(unsigned u) {
  union { unsigned v; _Float16 h[2]; } c; c.v = u;
  return make_float2((float)c.h[0], (float)c.h[1]);
}
__device__ inline half2t as_h2(unsigned u) {
  union { unsigned v; half2t h; } c; c.v = u;
  return c.h;
}
__device__ inline unsigned as_u32(half2t h) {
  union { half2t h; unsigned v; } c; c.h = h;
  return c.v;
}
__device__ inline unsigned pkadd(unsigned a, unsigned b) {
  return as_u32(as_h2(a) + as_h2(b));   // v_pk_add_f16
}
__device__ inline void pkacc4(uint4& A, const uint4& v) {
  A.x = pkadd(A.x, v.x); A.y = pkadd(A.y, v.y);
  A.z = pkadd(A.z, v.z); A.w = pkadd(A.w, v.w);
}

// ---------------- core gather: 1 node/wave, 16 col-lanes x 4 edge slots --------------
__device__ inline uint4 gather_rows(const unsigned* __restrict__ yzu,
                                    const int* __restrict__ sorted_src,
                                    int start, int end, int cl, int slot) {
  uint4 A0 = make_uint4(0u, 0u, 0u, 0u);
  uint4 A1 = A0;
  int k = start + slot;
  for (; k + 12 < end; k += 16) {
    int s0 = sorted_src[k];
    int s1 = sorted_src[k + 4];
    int s2 = sorted_src[k + 8];
    int s3 = sorted_src[k + 12];
    uint4 v0 = *(const uint4*)(yzu + (size_t)s0 * 128 + cl * 4);
    uint4 v1 = *(const uint4*)(yzu + (size_t)s1 * 128 + cl * 4);
    uint4 v2 = *(const uint4*)(yzu + (size_t)s2 * 128 + cl * 4);
    uint4 v3 = *(const uint4*)(yzu + (size_t)s3 * 128 + cl * 4);
    pkacc4(A0, v0);
    pkacc4(A1, v1);
    pkacc4(A0, v2);
    pkacc4(A1, v3);
  }
  if (k + 4 < end) {   // 2-deep tail
    int s0 = sorted_src[k];
    int s1 = sorted_src[k + 4];
    uint4 v0 = *(const uint4*)(yzu + (size_t)s0 * 128 + cl * 4);
    uint4 v1 = *(const uint4*)(yzu + (size_t)s1 * 128 + cl * 4);
    pkacc4(A0, v0);
    pkacc4(A1, v1);
    k += 8;
  }
  if (k < end) {
    int s = sorted_src[k];
    uint4 v = *(const uint4*)(yzu + (size_t)s * 128 + cl * 4);
    pkacc4(A0, v);
  }
  pkacc4(A0, A1);
#pragma unroll
  for (int off = 16; off < 64; off <<= 1) {
    uint4 o;
    o.x = (unsigned)__shfl_xor((int)A0.x, off, 64);
    o.y = (unsigned)__shfl_xor((int)A0.y, off, 64);
    o.z = (unsigned)__shfl_xor((int)A0.z, off, 64);
    o.w = (unsigned)__shfl_xor((int)A0.w, off, 64);
    pkacc4(A0, o);
  }
  return A0;
}

// ---------------- layer-1 aggregate + combine + ReLU ----------------
__global__ __launch_bounds__(256) void agg_relu16(
    const unsigned* __restrict__ yzu, const int* __restrict__ sorted_src,
    const int* __restrict__ rs, const int* __restrict__ re,
    const float* __restrict__ bias, unsigned* __restrict__ h1u, int N) {
  const int w = threadIdx.x >> 6;
  const int lane = threadIdx.x & 63;
  const int cl = lane & 15;
  const int slot = lane >> 4;
  const int node = blockIdx.x * 4 + w;
  if (node >= N) return;
  const int start = rs[node];
  const int end = re[node];
  uint4 A = gather_rows(yzu, sorted_src, start, end, cl, slot);
  if (slot == 0) {
    const int deg = end - start;
    const float inv = 1.f / (float)max(deg, 1);
    uint4 z4 = *(const uint4*)(yzu + (size_t)node * 128 + 64 + cl * 4);
    const unsigned av[4] = {A.x, A.y, A.z, A.w};
    const unsigned zv[4] = {z4.x, z4.y, z4.z, z4.w};
    uint4 o;
    unsigned ov[4];
#pragma unroll
    for (int q = 0; q < 4; ++q) {
      const int cp = cl * 4 + q;
      float2 a = upk(av[q]);
      float2 z = upk(zv[q]);
      float vx = fmaxf(a.x * inv + bias[2 * cp] + z.x, 0.f);
      float vy = fmaxf(a.y * inv + bias[2 * cp + 1] + z.y, 0.f);
      union { unsigned v; _Float16 h[2]; } c;
      c.h[0] = (_Float16)vx; c.h[1] = (_Float16)vy;
      ov[q] = c.v;
    }
    o.x = ov[0]; o.y = ov[1]; o.z = ov[2]; o.w = ov[3];
    *(uint4*)(h1u + (size_t)node * 64 + cl * 4) = o;
  }
}

// ---------------- layer-2 aggregate + combine + fused scorer projection --------------
__global__ __launch_bounds__(256) void agg_score16(
    const unsigned* __restrict__ yzu, const int* __restrict__ sorted_src,
    const int* __restrict__ rs, const int* __restrict__ re,
    const float* __restrict__ bias, const float* __restrict__ Wlin,
    float* __restrict__ sa, float* __restrict__ sb, int N) {
  const int w = threadIdx.x >> 6;
  const int lane = threadIdx.x & 63;
  const int cl = lane & 15;
  const int slot = lane >> 4;
  const int node = blockIdx.x * 4 + w;
  if (node >= N) return;
  const int start = rs[node];
  const int end = re[node];
  uint4 A = gather_rows(yzu, sorted_src, start, end, cl, slot);
  const int deg = end - start;
  const float inv = 1.f / (float)max(deg, 1);
  uint4 z4 = *(const uint4*)(yzu + (size_t)node * 128 + 64 + cl * 4);
  const unsigned av[4] = {A.x, A.y, A.z, A.w};
  const unsigned zv[4] = {z4.x, z4.y, z4.z, z4.w};
  float pa = 0.f, pb = 0.f;
#pragma unroll
  for (int q = 0; q < 4; ++q) {
    const int cp = cl * 4 + q;
    float2 a = upk(av[q]);
    float2 z = upk(zv[q]);
    float hx = a.x * inv + bias[2 * cp] + z.x;
    float hy = a.y * inv + bias[2 * cp + 1] + z.y;
    pa += hx * Wlin[2 * cp] + hy * Wlin[2 * cp + 1];
    pb += hx * Wlin[128 + 2 * cp] + hy * Wlin[129 + 2 * cp];
  }
#pragma unroll
  for (int off = 1; off < 16; off <<= 1) {
    pa += __shfl_xor(pa, off, 64);
    pb += __shfl_xor(pb, off, 64);
  }
  if (lane == 0) {
    sa[node] = pa;
    sb[node] = pb;
  }
}

// ---------------- edge scoring (both pos and neg in one launch) ----------------
__global__ void score2(const int* __restrict__ pos, const int* __restrict__ neg,
                       int Ep, int En,
                       const float* __restrict__ sa, const float* __restrict__ sb,
                       const float* __restrict__ blin, float* __restrict__ out) {
  int e = blockIdx.x * 256 + threadIdx.x;
  if (e < Ep) {
    out[e] = sa[pos[e]] + sb[pos[Ep + e]] + blin[0];
  } else if (e < Ep + En) {
    int i = e - Ep;
    out[Ep + i] = sa[neg[i]] + sb[neg[En + i]] + blin[0];
  }
}

extern "C" void kernel_launch(void* const* d_in, const int* in_sizes, int n_in,
                              void* d_out, int out_size, void* d_ws, size_t ws_size,
                              hipStream_t stream) {
  (void)n_in; (void)out_size; (void)ws_size;
  const float* x    = (const float*)d_in[0];
  const int*   ei   = (const int*)d_in[1];
  const int*   pos  = (const int*)d_in[2];
  const int*   neg  = (const int*)d_in[3];
  const float* Wl1  = (const float*)d_in[4];
  const float* bl1  = (const float*)d_in[5];
  const float* Wr1  = (const float*)d_in[6];
  const float* Wl2  = (const float*)d_in[7];
  const float* bl2  = (const float*)d_in[8];
  const float* Wr2  = (const float*)d_in[9];
  const float* Wlin = (const float*)d_in[10];
  const float* blin = (const float*)d_in[11];

  const int N  = in_sizes[0] / IN_DIM;  // 100000
  const int E  = in_sizes[1] / 2;       // 3200000
  const int Ep = in_sizes[2] / 2;       // 500000
  const int En = in_sizes[3] / 2;       // 500000
  const int* e_src = ei;
  const int* e_dst = ei + E;

  char* ws = (char*)d_ws;
  size_t off = 0;
  auto carve = [&](size_t bytes) -> char* {
    char* p = ws + off;
    off += (bytes + 255) & ~(size_t)255;
    return p;
  };
  const int KS1 = IN_DIM / 32;          // 12
  const int KS2 = HID / 32;             // 4
  const int scanBlocks = (N + 255) / 256;   // 391

  int*      rs     = (int*)carve((size_t)N * 4);
  int*      re     = (int*)carve((size_t)N * 4);
  int*      cnt    = (int*)carve((size_t)N * 4);
  int*      cur    = (int*)carve((size_t)N * 4);
  int*      bsum   = (int*)carve(512 * 4);
  int*      sorted = (int*)carve((size_t)E * 4);
  float*    sa     = (float*)carve((size_t)N * 4);
  float*    sb     = (float*)carve((size_t)N * 4);
  _Float16* Bp1    = (_Float16*)carve((size_t)16 * KS1 * 64 * 8 * 2);
  _Float16* Bp2    = (_Float16*)carve((size_t)16 * KS2 * 64 * 8 * 2);
  _Float16* yz     = (_Float16*)carve((size_t)N * 256 * 2);
  _Float16* h1     = (_Float16*)carve((size_t)N * 128 * 2);

  const int gemmBlocks = (N + 127) / 128;

  // ---- exact CSR build: hist -> 3-step scan -> scatter ----
  hipLaunchKernelGGL(zero_i32, dim3(scanBlocks), dim3(256), 0, stream, cnt, N);
  hipLaunchKernelGGL(hist_kernel, dim3(2048), dim3(256), 0, stream, e_dst, E, cnt);
  hipLaunchKernelGGL(scan_block, dim3(scanBlocks), dim3(256), 0, stream,
                     cnt, N, rs, bsum);
  hipLaunchKernelGGL(scan_top, dim3(1), dim3(512), 0, stream, bsum, scanBlocks);
  hipLaunchKernelGGL(scan_add, dim3(scanBlocks), dim3(256), 0, stream,
                     cnt, bsum, N, rs, re, cur);
  hipLaunchKernelGGL(scatter_kernel, dim3(2048), dim3(256), 0, stream,
                     e_src, e_dst, E, cur, sorted);

  // weight packing
  hipLaunchKernelGGL(pack_w2, dim3(8, KS1, 2), dim3(64), 0, stream, Wl1, Wr1, Bp1);
  hipLaunchKernelGGL(pack_w2, dim3(8, KS2, 2), dim3(64), 0, stream, Wl2, Wr2, Bp2);

  // layer 1
  hipLaunchKernelGGL(gemm_f32a, dim3(gemmBlocks), dim3(512), 0, stream,
                     x, N, Bp1, yz);
  hipLaunchKernelGGL(agg_relu16, dim3((N + 3) / 4), dim3(256), 0, stream,
                     (const unsigned*)yz, sorted, rs, re, bl1, (unsigned*)h1, N);
  // layer 2
  hipLaunchKernelGGL(gemm_f16a, dim3(gemmBlocks), dim3(512), 0, stream,
                     h1, N, Bp2, yz);
  hipLaunchKernelGGL(agg_score16, dim3((N + 3) / 4), dim3(256), 0, stream,
                     (const unsigned*)yz, sorted, rs, re, bl2, Wlin, sa, sb, N);

  // scoring (single launch)
  float* out = (float*)d_out;
  hipLaunchKernelGGL(score2, dim3((Ep + En + 255) / 256), dim3(256), 0, stream,
                     pos, neg, Ep, En, sa, sb, blin, out);
}

// Round 6
// 553.851 us; speedup vs baseline: 1.6456x; 1.6456x over previous
//
#include <hip/hip_runtime.h>

#define IN_DIM 384
#define HID    128
#define NPB    256            // nodes per bucket (dstLocal fits in 8 bits)
#define BCAP   16384          // fixed bucket capacity (max fill ~8.7k, 1.9x margin)
#define LCAP   10240          // LDS-resident bucket capacity (40KB)

#define AS1 __attribute__((address_space(1)))
#define AS3 __attribute__((address_space(3)))

typedef _Float16 half8 __attribute__((ext_vector_type(8)));
typedef _Float16 half2t __attribute__((ext_vector_type(2)));
typedef __fp16 fp16x2 __attribute__((ext_vector_type(2)));
typedef float floatx4 __attribute__((ext_vector_type(4)));
typedef float floatx2 __attribute__((ext_vector_type(2)));

// ---------------- utility ----------------
__global__ void zero_i32(int* __restrict__ p, int n) {
  int i = blockIdx.x * 256 + threadIdx.x;
  if (i < n) p[i] = 0;
}

// ---------------- phase 1: partition edges into fixed-capacity coarse buckets -------
// 8192 edges/block, 512 threads (8 waves); packed value = (dstLocal << 17) | src
__global__ __launch_bounds__(512) void partition_kernel(
    const int* __restrict__ src, const int* __restrict__ dst, int E, int nB,
    int* __restrict__ bCur, unsigned* __restrict__ bucketData) {
  __shared__ int hist[391];
  __shared__ int gbase[391];
  const int t = threadIdx.x;
  const int b0 = blockIdx.x * 8192;

  for (int i = t; i < nB; i += 512) hist[i] = 0;
  __syncthreads();
#pragma unroll
  for (int i = 0; i < 16; ++i) {
    int e = b0 + i * 512 + t;
    if (e < E) atomicAdd(&hist[dst[e] >> 8], 1);
  }
  __syncthreads();
  for (int i = t; i < nB; i += 512) {
    int h = hist[i];
    gbase[i] = h ? (i * BCAP + atomicAdd(&bCur[i], h)) : 0;
    hist[i] = 0;
  }
  __syncthreads();
#pragma unroll
  for (int i = 0; i < 16; ++i) {
    int e = b0 + i * 512 + t;
    if (e < E) {
      int d = dst[e];
      int b = d >> 8;
      int r = atomicAdd(&hist[b], 1);
      bucketData[gbase[b] + r] = ((unsigned)(d & 255) << 17) | (unsigned)src[e];
    }
  }
}

// ---------------- phase 2: per-bucket node histogram + scan + scatter ----------------
__global__ __launch_bounds__(1024) void node_sort3(
    const unsigned* __restrict__ bucketData, const int* __restrict__ bCur,
    int N, int* __restrict__ sorted_src, int* __restrict__ rs, int* __restrict__ re) {
  extern __shared__ unsigned sdata[];          // LCAP entries
  __shared__ int hist[NPB];
  __shared__ int s[NPB];
  __shared__ int cur[NPB];
  const int b = blockIdx.x;
  const int t = threadIdx.x;
  const int start = b * BCAP;
  const int fill = bCur[b];
  if (t < NPB) hist[t] = 0;
  __syncthreads();
  // stage + histogram in one pass
  for (int i = t; i < fill; i += 1024) {
    unsigned d = bucketData[start + i];
    if (i < LCAP) sdata[i] = d;
    atomicAdd(&hist[d >> 17], 1);
  }
  __syncthreads();
  int v = 0;
  if (t < NPB) { v = hist[t]; s[t] = v; }
  __syncthreads();
  for (int off = 1; off < NPB; off <<= 1) {
    int y = (t < NPB && t >= off) ? s[t - off] : 0;
    __syncthreads();
    if (t < NPB) s[t] += y;
    __syncthreads();
  }
  if (t < NPB) {
    int excl = s[t] - v;
    const int node = b * NPB + t;
    if (node < N) {
      rs[node] = start + excl;
      re[node] = start + excl + v;
    }
    cur[t] = start + excl;
  }
  __syncthreads();
  for (int i = t; i < fill; i += 1024) {
    unsigned d = (i < LCAP) ? sdata[i] : bucketData[start + i];
    int p = atomicAdd(&cur[d >> 17], 1);
    sorted_src[p] = (int)(d & 0x1FFFF);
  }
}

// ---------------- weight pack: W[K][128] fp32 -> per-lane MFMA B-fragment order ------
__global__ void pack_w2(const float* __restrict__ Wl, const float* __restrict__ Wr,
                        _Float16* __restrict__ Bp) {
  const float* __restrict__ W = blockIdx.z ? Wr : Wl;
  const int tn = blockIdx.x;
  const int ks = blockIdx.y;
  const int KS = gridDim.y;
  const int lane = threadIdx.x;
  const int n = tn * 16 + (lane & 15);
  const int kb = ks * 32 + (lane >> 4) * 8;
  half8 v;
#pragma unroll
  for (int j = 0; j < 8; ++j) v[j] = (_Float16)W[(size_t)(kb + j) * HID + n];
  *(half8*)(Bp + (((size_t)(blockIdx.z * 8 + tn) * KS + ks) * 64 + lane) * 8) = v;
}

// ---------------- cvt helper: pack two fp32 -> fp16x2 (RTZ), as half2t --------------
__device__ inline half2t cvt_pk(float a, float b) {
  fp16x2 r = __builtin_amdgcn_cvt_pkrtz(a, b);
  union { fp16x2 f; half2t h; } c;
  c.f = r;
  return c.h;
}

// ---------------- GEMM (fp32 A), layer 1: y8[M x 128] fp8 e4m3 + z1[M x 128] fp16 ----
// y = A @ Bl (gathered by agg -> fp8 halves gather traffic); z = A @ Br (read once,
// sequential -> fp16).
__global__ __launch_bounds__(512) void gemm_f32a(
    const float* __restrict__ A, int M,
    const _Float16* __restrict__ Bp,
    unsigned char* __restrict__ y8, _Float16* __restrict__ z1) {
  __shared__ float As[128 * 32];   // (row*8 + cg_phys)*4 floats, cg_phys = cg ^ (row&7)

  const int K = IN_DIM, KS = IN_DIM / 32;
  const int tid = threadIdx.x;
  const int lane = tid & 63;
  const int wid = tid >> 6;
  const int quad = lane >> 4;
  const int lm = lane & 15;
  const int row0 = (wid & 1) * 64;
  const int ct0 = (wid >> 1) * 4;
  const int blockRow = blockIdx.x * 128;

  const int srow = lane >> 3;
  const int scol = ((lane & 7) ^ (srow & 7)) * 4;
  const int grow0 = min(blockRow + wid * 16 + srow, M - 1);
  const int grow1 = min(blockRow + wid * 16 + 8 + srow, M - 1);

  floatx4 acc[16];
#pragma unroll
  for (int i = 0; i < 16; ++i) {
    acc[i][0] = 0.f; acc[i][1] = 0.f; acc[i][2] = 0.f; acc[i][3] = 0.f;
  }

  for (int ks = 0; ks < KS; ++ks) {
    const int k0 = ks * 32;
    __syncthreads();
    __builtin_amdgcn_global_load_lds(
        (const AS1 void*)(A + (size_t)grow0 * K + k0 + scol),
        (AS3 void*)(As + (wid * 16) * 32), 16, 0, 0);
    __builtin_amdgcn_global_load_lds(
        (const AS1 void*)(A + (size_t)grow1 * K + k0 + scol),
        (AS3 void*)(As + (wid * 16 + 8) * 32), 16, 0, 0);

    half8 bf[4];
#pragma unroll
    for (int ct = 0; ct < 4; ++ct)
      bf[ct] = *(const half8*)(Bp + (((size_t)(ct0 + ct) * KS + ks) * 64 + lane) * 8);

    __syncthreads();

    half8 af[4];
#pragma unroll
    for (int rt = 0; rt < 4; ++rt) {
      const int row = row0 + rt * 16 + lm;
      const int sw = row & 7;
      const floatx4 fA = *(const floatx4*)&As[(row * 8 + ((quad * 2) ^ sw)) * 4];
      const floatx4 fB = *(const floatx4*)&As[(row * 8 + ((quad * 2 + 1) ^ sw)) * 4];
      half2t h01 = cvt_pk(fA[0], fA[1]);
      half2t h23 = cvt_pk(fA[2], fA[3]);
      half2t h45 = cvt_pk(fB[0], fB[1]);
      half2t h67 = cvt_pk(fB[2], fB[3]);
      half8 a;
      a[0] = h01[0]; a[1] = h01[1]; a[2] = h23[0]; a[3] = h23[1];
      a[4] = h45[0]; a[5] = h45[1]; a[6] = h67[0]; a[7] = h67[1];
      af[rt] = a;
    }
#pragma unroll
    for (int rt = 0; rt < 4; ++rt)
#pragma unroll
      for (int ct = 0; ct < 4; ++ct)
        acc[rt * 4 + ct] =
            __builtin_amdgcn_mfma_f32_16x16x32_f16(af[rt], bf[ct], acc[rt * 4 + ct], 0, 0, 0);
  }

#pragma unroll
  for (int rt = 0; rt < 4; ++rt) {
#pragma unroll
    for (int r = 0; r < 4; ++r) {
      const int gm = blockRow + row0 + rt * 16 + quad * 4 + r;
      if (gm < M) {
#pragma unroll
        for (int ct = 0; ct < 4; ++ct) {
          const int tn = ct0 + ct;
          const float v = acc[rt * 4 + ct][r];
          if (tn < 8) {
            int p = __builtin_amdgcn_cvt_pk_fp8_f32(v, v, 0, false);
            y8[(size_t)gm * 128 + tn * 16 + lm] = (unsigned char)(p & 0xFF);
          } else {
            z1[(size_t)gm * 128 + (tn - 8) * 16 + lm] = (_Float16)v;
          }
        }
      }
    }
  }
}

// ---------------- GEMM (fp16 A), layer 2: C[M x 256] fp16 = A[M x 128] @ [Bl | Br] ---
__global__ __launch_bounds__(512) void gemm_f16a(
    const _Float16* __restrict__ A, int M,
    const _Float16* __restrict__ Bp, _Float16* __restrict__ C) {
  __shared__ _Float16 As[128 * 32];  // (row*4 + cg_phys)*8 halfs

  const int K = HID, KS = HID / 32;
  const int tid = threadIdx.x;
  const int lane = tid & 63;
  const int wid = tid >> 6;
  const int quad = lane >> 4;
  const int lm = lane & 15;
  const int row0 = (wid & 1) * 64;
  const int ct0 = (wid >> 1) * 4;
  const int blockRow = blockIdx.x * 128;

  const int srow = lane >> 2;
  const int scol = ((lane & 3) ^ ((lane >> 3) & 3)) * 8;
  const int grow = min(blockRow + wid * 16 + srow, M - 1);

  floatx4 acc[16];
#pragma unroll
  for (int i = 0; i < 16; ++i) {
    acc[i][0] = 0.f; acc[i][1] = 0.f; acc[i][2] = 0.f; acc[i][3] = 0.f;
  }

  for (int ks = 0; ks < KS; ++ks) {
    const int k0 = ks * 32;
    __syncthreads();
    __builtin_amdgcn_global_load_lds(
        (const AS1 void*)(A + (size_t)grow * K + k0 + scol),
        (AS3 void*)(As + (wid * 16) * 32), 16, 0, 0);

    half8 bf[4];
#pragma unroll
    for (int ct = 0; ct < 4; ++ct)
      bf[ct] = *(const half8*)(Bp + (((size_t)(ct0 + ct) * KS + ks) * 64 + lane) * 8);

    __syncthreads();

    half8 af[4];
#pragma unroll
    for (int rt = 0; rt < 4; ++rt) {
      const int row = row0 + rt * 16 + lm;
      const int cg = quad ^ ((row >> 1) & 3);
      af[rt] = *(const half8*)&As[(row * 4 + cg) * 8];
    }
#pragma unroll
    for (int rt = 0; rt < 4; ++rt)
#pragma unroll
      for (int ct = 0; ct < 4; ++ct)
        acc[rt * 4 + ct] =
            __builtin_amdgcn_mfma_f32_16x16x32_f16(af[rt], bf[ct], acc[rt * 4 + ct], 0, 0, 0);
  }

#pragma unroll
  for (int rt = 0; rt < 4; ++rt) {
#pragma unroll
    for (int r = 0; r < 4; ++r) {
      const int gm = blockRow + row0 + rt * 16 + quad * 4 + r;
      if (gm < M) {
#pragma unroll
        for (int ct = 0; ct < 4; ++ct)
          C[(size_t)gm * 256 + (ct0 + ct) * 16 + lm] = (_Float16)acc[rt * 4 + ct][r];
      }
    }
  }
}

// ---------------- helpers ----------------
__device__ inline float2 upk(unsigned u) {
  union { unsigned v; _Float16 h[2]; } c; c.v = u;
  return make_float2((float)c.h[0], (float)c.h[1]);
}
__device__ inline half2t as_h2(unsigned u) {
  union { unsigned v; half2t h; } c; c.v = u;
  return c.h;
}
__device__ inline unsigned as_u32(half2t h) {
  union { half2t h; unsigned v; } c; c.h = h;
  return c.v;
}
__device__ inline unsigned pkadd(unsigned a, unsigned b) {
  return as_u32(as_h2(a) + as_h2(b));   // v_pk_add_f16
}
__device__ inline void pkacc4(uint4& A, const uint4& v) {
  A.x = pkadd(A.x, v.x); A.y = pkadd(A.y, v.y);
  A.z = pkadd(A.z, v.z); A.w = pkadd(A.w, v.w);
}

// ---------------- fp8 gather accumulator: 8 fp8 -> 4x float2 pk-adds ----------------
struct f32acc8 { floatx2 a, b, c, d; };
__device__ inline void f8acc(f32acc8& A, uint2 v) {
  A.a += __builtin_amdgcn_cvt_pk_f32_fp8(v.x, false);
  A.b += __builtin_amdgcn_cvt_pk_f32_fp8(v.x, true);
  A.c += __builtin_amdgcn_cvt_pk_f32_fp8(v.y, false);
  A.d += __builtin_amdgcn_cvt_pk_f32_fp8(v.y, true);
}
__device__ inline void f8merge(f32acc8& A, const f32acc8& B) {
  A.a += B.a; A.b += B.b; A.c += B.c; A.d += B.d;
}

// ---------------- layer-1 gather (fp8 rows, 128B): 16 col-lanes x 4 edge slots -------
// lane cl holds cols [cl*8, cl*8+8) as 4 float2 accumulators.
__device__ inline f32acc8 gather_rows8(const unsigned char* __restrict__ y8,
                                       const int* __restrict__ sorted_src,
                                       int start, int end, int cl, int slot) {
  f32acc8 A0; A0.a = 0.f; A0.b = 0.f; A0.c = 0.f; A0.d = 0.f;
  f32acc8 A1 = A0;
  int k = start + slot;
  for (; k + 12 < end; k += 16) {
    int s0 = sorted_src[k];
    int s1 = sorted_src[k + 4];
    int s2 = sorted_src[k + 8];
    int s3 = sorted_src[k + 12];
    uint2 v0 = *(const uint2*)(y8 + (size_t)s0 * 128 + cl * 8);
    uint2 v1 = *(const uint2*)(y8 + (size_t)s1 * 128 + cl * 8);
    uint2 v2 = *(const uint2*)(y8 + (size_t)s2 * 128 + cl * 8);
    uint2 v3 = *(const uint2*)(y8 + (size_t)s3 * 128 + cl * 8);
    f8acc(A0, v0);
    f8acc(A1, v1);
    f8acc(A0, v2);
    f8acc(A1, v3);
  }
  if (k + 4 < end) {   // 2-deep tail
    int s0 = sorted_src[k];
    int s1 = sorted_src[k + 4];
    uint2 v0 = *(const uint2*)(y8 + (size_t)s0 * 128 + cl * 8);
    uint2 v1 = *(const uint2*)(y8 + (size_t)s1 * 128 + cl * 8);
    f8acc(A0, v0);
    f8acc(A1, v1);
    k += 8;
  }
  if (k < end) {
    uint2 v = *(const uint2*)(y8 + (size_t)sorted_src[k] * 128 + cl * 8);
    f8acc(A0, v);
  }
  f8merge(A0, A1);
#pragma unroll
  for (int off = 16; off < 64; off <<= 1) {
    f32acc8 o;
    o.a[0] = __shfl_xor(A0.a[0], off, 64); o.a[1] = __shfl_xor(A0.a[1], off, 64);
    o.b[0] = __shfl_xor(A0.b[0], off, 64); o.b[1] = __shfl_xor(A0.b[1], off, 64);
    o.c[0] = __shfl_xor(A0.c[0], off, 64); o.c[1] = __shfl_xor(A0.c[1], off, 64);
    o.d[0] = __shfl_xor(A0.d[0], off, 64); o.d[1] = __shfl_xor(A0.d[1], off, 64);
    f8merge(A0, o);
  }
  return A0;
}

// ---------------- layer-1 aggregate + combine + ReLU (fp8 y, fp16 z) ----------------
__global__ __launch_bounds__(256) void agg_relu8(
    const unsigned char* __restrict__ y8, const unsigned* __restrict__ z1u,
    const int* __restrict__ sorted_src,
    const int* __restrict__ rs, const int* __restrict__ re,
    const float* __restrict__ bias, unsigned* __restrict__ h1u, int N) {
  const int w = threadIdx.x >> 6;
  const int lane = threadIdx.x & 63;
  const int cl = lane & 15;
  const int slot = lane >> 4;
  const int node = blockIdx.x * 4 + w;
  if (node >= N) return;
  const int start = rs[node];
  const int end = re[node];
  f32acc8 A = gather_rows8(y8, sorted_src, start, end, cl, slot);
  if (slot == 0) {
    const int deg = end - start;
    const float inv = 1.f / (float)max(deg, 1);
    uint4 z4 = *(const uint4*)(z1u + (size_t)node * 64 + cl * 4);
    const unsigned zv[4] = {z4.x, z4.y, z4.z, z4.w};
    const floatx2 av[4] = {A.a, A.b, A.c, A.d};
    unsigned ov[4];
#pragma unroll
    for (int q = 0; q < 4; ++q) {
      const int c = cl * 8 + q * 2;
      float2 z = upk(zv[q]);
      float vx = fmaxf(av[q][0] * inv + bias[c] + z.x, 0.f);
      float vy = fmaxf(av[q][1] * inv + bias[c + 1] + z.y, 0.f);
      union { unsigned v; _Float16 h[2]; } cc;
      cc.h[0] = (_Float16)vx; cc.h[1] = (_Float16)vy;
      ov[q] = cc.v;
    }
    uint4 o;
    o.x = ov[0]; o.y = ov[1]; o.z = ov[2]; o.w = ov[3];
    *(uint4*)(h1u + (size_t)node * 64 + cl * 4) = o;
  }
}

// ---------------- layer-2 gather (fp16 rows, 256B): unchanged round-0 path -----------
__device__ inline uint4 gather_rows(const unsigned* __restrict__ yzu,
                                    const int* __restrict__ sorted_src,
                                    int start, int end, int cl, int slot) {
  uint4 A0 = make_uint4(0u, 0u, 0u, 0u);
  uint4 A1 = A0;
  int k = start + slot;
  for (; k + 12 < end; k += 16) {
    int s0 = sorted_src[k];
    int s1 = sorted_src[k + 4];
    int s2 = sorted_src[k + 8];
    int s3 = sorted_src[k + 12];
    uint4 v0 = *(const uint4*)(yzu + (size_t)s0 * 128 + cl * 4);
    uint4 v1 = *(const uint4*)(yzu + (size_t)s1 * 128 + cl * 4);
    uint4 v2 = *(const uint4*)(yzu + (size_t)s2 * 128 + cl * 4);
    uint4 v3 = *(const uint4*)(yzu + (size_t)s3 * 128 + cl * 4);
    pkacc4(A0, v0);
    pkacc4(A1, v1);
    pkacc4(A0, v2);
    pkacc4(A1, v3);
  }
  if (k + 4 < end) {   // 2-deep tail
    int s0 = sorted_src[k];
    int s1 = sorted_src[k + 4];
    uint4 v0 = *(const uint4*)(yzu + (size_t)s0 * 128 + cl * 4);
    uint4 v1 = *(const uint4*)(yzu + (size_t)s1 * 128 + cl * 4);
    pkacc4(A0, v0);
    pkacc4(A1, v1);
    k += 8;
  }
  if (k < end) {
    int s = sorted_src[k];
    uint4 v = *(const uint4*)(yzu + (size_t)s * 128 + cl * 4);
    pkacc4(A0, v);
  }
  pkacc4(A0, A1);
#pragma unroll
  for (int off = 16; off < 64; off <<= 1) {
    uint4 o;
    o.x = (unsigned)__shfl_xor((int)A0.x, off, 64);
    o.y = (unsigned)__shfl_xor((int)A0.y, off, 64);
    o.z = (unsigned)__shfl_xor((int)A0.z, off, 64);
    o.w = (unsigned)__shfl_xor((int)A0.w, off, 64);
    pkacc4(A0, o);
  }
  return A0;
}

// ---------------- layer-2 aggregate + combine + fused scorer projection --------------
__global__ __launch_bounds__(256) void agg_score16(
    const unsigned* __restrict__ yzu, const int* __restrict__ sorted_src,
    const int* __restrict__ rs, const int* __restrict__ re,
    const float* __restrict__ bias, const float* __restrict__ Wlin,
    float* __restrict__ sa, float* __restrict__ sb, int N) {
  const int w = threadIdx.x >> 6;
  const int lane = threadIdx.x & 63;
  const int cl = lane & 15;
  const int slot = lane >> 4;
  const int node = blockIdx.x * 4 + w;
  if (node >= N) return;
  const int start = rs[node];
  const int end = re[node];
  uint4 A = gather_rows(yzu, sorted_src, start, end, cl, slot);
  const int deg = end - start;
  const float inv = 1.f / (float)max(deg, 1);
  uint4 z4 = *(const uint4*)(yzu + (size_t)node * 128 + 64 + cl * 4);
  const unsigned av[4] = {A.x, A.y, A.z, A.w};
  const unsigned zv[4] = {z4.x, z4.y, z4.z, z4.w};
  float pa = 0.f, pb = 0.f;
#pragma unroll
  for (int q = 0; q < 4; ++q) {
    const int cp = cl * 4 + q;
    float2 a = upk(av[q]);
    float2 z = upk(zv[q]);
    float hx = a.x * inv + bias[2 * cp] + z.x;
    float hy = a.y * inv + bias[2 * cp + 1] + z.y;
    pa += hx * Wlin[2 * cp] + hy * Wlin[2 * cp + 1];
    pb += hx * Wlin[128 + 2 * cp] + hy * Wlin[129 + 2 * cp];
  }
#pragma unroll
  for (int off = 1; off < 16; off <<= 1) {
    pa += __shfl_xor(pa, off, 64);
    pb += __shfl_xor(pb, off, 64);
  }
  if (lane == 0) {
    sa[node] = pa;
    sb[node] = pb;
  }
}

// ---------------- edge scoring (both pos and neg in one launch) ----------------
__global__ void score2(const int* __restrict__ pos, const int* __restrict__ neg,
                       int Ep, int En,
                       const float* __restrict__ sa, const float* __restrict__ sb,
                       const float* __restrict__ blin, float* __restrict__ out) {
  int e = blockIdx.x * 256 + threadIdx.x;
  if (e < Ep) {
    out[e] = sa[pos[e]] + sb[pos[Ep + e]] + blin[0];
  } else if (e < Ep + En) {
    int i = e - Ep;
    out[Ep + i] = sa[neg[i]] + sb[neg[En + i]] + blin[0];
  }
}

extern "C" void kernel_launch(void* const* d_in, const int* in_sizes, int n_in,
                              void* d_out, int out_size, void* d_ws, size_t ws_size,
                              hipStream_t stream) {
  (void)n_in; (void)out_size; (void)ws_size;
  const float* x    = (const float*)d_in[0];
  const int*   ei   = (const int*)d_in[1];
  const int*   pos  = (const int*)d_in[2];
  const int*   neg  = (const int*)d_in[3];
  const float* Wl1  = (const float*)d_in[4];
  const float* bl1  = (const float*)d_in[5];
  const float* Wr1  = (const float*)d_in[6];
  const float* Wl2  = (const float*)d_in[7];
  const float* bl2  = (const float*)d_in[8];
  const float* Wr2  = (const float*)d_in[9];
  const float* Wlin = (const float*)d_in[10];
  const float* blin = (const float*)d_in[11];

  const int N  = in_sizes[0] / IN_DIM;  // 100000
  const int E  = in_sizes[1] / 2;       // 3200000
  const int Ep = in_sizes[2] / 2;       // 500000
  const int En = in_sizes[3] / 2;       // 500000
  const int* e_src = ei;
  const int* e_dst = ei + E;

  char* ws = (char*)d_ws;
  size_t off = 0;
  auto carve = [&](size_t bytes) -> char* {
    char* p = ws + off;
    off += (bytes + 255) & ~(size_t)255;
    return p;
  };
  const int nB = (N + NPB - 1) / NPB;   // 391 buckets
  const int KS1 = IN_DIM / 32;          // 12
  const int KS2 = HID / 32;             // 4

  int*      rs     = (int*)carve((size_t)N * 4);
  int*      re     = (int*)carve((size_t)N * 4);
  int*      bCur   = (int*)carve(512 * 4);
  unsigned* bData  = (unsigned*)carve((size_t)nB * BCAP * 4);
  int*      sorted = (int*)carve((size_t)nB * BCAP * 4);
  float*    sa     = (float*)carve((size_t)N * 4);
  float*    sb     = (float*)carve((size_t)N * 4);
  _Float16* Bp1    = (_Float16*)carve((size_t)16 * KS1 * 64 * 8 * 2);
  _Float16* Bp2    = (_Float16*)carve((size_t)16 * KS2 * 64 * 8 * 2);
  _Float16* yz     = (_Float16*)carve((size_t)N * 256 * 2);   // 51.2 MB block
  _Float16* h1     = (_Float16*)carve((size_t)N * 128 * 2);

  // layer-1 outputs overlay the yz block (dead before gemm_f16a writes yz):
  //   y8: N x 128 fp8 (12.8 MB), z1: N x 128 fp16 (25.6 MB)
  unsigned char* y8 = (unsigned char*)yz;
  _Float16*      z1 = (_Float16*)(y8 + (size_t)N * 128);

  const int gemmBlocks = (N + 127) / 128;
  const int partBlocks = (E + 8191) / 8192;  // 391

  // CSR build
  hipLaunchKernelGGL(zero_i32, dim3(2), dim3(256), 0, stream, bCur, 512);
  hipLaunchKernelGGL(partition_kernel, dim3(partBlocks), dim3(512), 0, stream,
                     e_src, e_dst, E, nB, bCur, bData);
  hipLaunchKernelGGL(node_sort3, dim3(nB), dim3(1024), LCAP * 4, stream,
                     bData, bCur, N, sorted, rs, re);

  // weight packing
  hipLaunchKernelGGL(pack_w2, dim3(8, KS1, 2), dim3(64), 0, stream, Wl1, Wr1, Bp1);
  hipLaunchKernelGGL(pack_w2, dim3(8, KS2, 2), dim3(64), 0, stream, Wl2, Wr2, Bp2);

  // layer 1 (y in fp8 for the gather, z in fp16)
  hipLaunchKernelGGL(gemm_f32a, dim3(gemmBlocks), dim3(512), 0, stream,
                     x, N, Bp1, y8, z1);
  hipLaunchKernelGGL(agg_relu8, dim3((N + 3) / 4), dim3(256), 0, stream,
                     y8, (const unsigned*)z1, sorted, rs, re, bl1, (unsigned*)h1, N);
  // layer 2 (fp16 throughout)
  hipLaunchKernelGGL(gemm_f16a, dim3(gemmBlocks), dim3(512), 0, stream,
                     h1, N, Bp2, yz);
  hipLaunchKernelGGL(agg_score16, dim3((N + 3) / 4), dim3(256), 0, stream,
                     (const unsigned*)yz, sorted, rs, re, bl2, Wlin, sa, sb, N);

  // scoring (single launch)
  float* out = (float*)d_out;
  hipLaunchKernelGGL(score2, dim3((Ep + En + 255) / 256), dim3(256), 0, stream,
                     pos, neg, Ep, En, sa, sb, blin, out);
}

// Round 7
// 476.061 us; speedup vs baseline: 1.9144x; 1.1634x over previous
//
#include <hip/hip_runtime.h>

#define IN_DIM 384
#define HID    128
#define NPB    256            // nodes per bucket (dstLocal fits in 8 bits)
#define BCAP   16384          // fixed bucket capacity (max fill ~8.7k, 1.9x margin)
#define LCAP   10240          // LDS-resident bucket capacity (40KB)

#define AS1 __attribute__((address_space(1)))
#define AS3 __attribute__((address_space(3)))

typedef _Float16 half8 __attribute__((ext_vector_type(8)));
typedef _Float16 half2t __attribute__((ext_vector_type(2)));
typedef __fp16 fp16x2 __attribute__((ext_vector_type(2)));
typedef float floatx4 __attribute__((ext_vector_type(4)));
typedef float floatx2 __attribute__((ext_vector_type(2)));

// ---------------- utility ----------------
__global__ void zero_i32(int* __restrict__ p, int n) {
  int i = blockIdx.x * 256 + threadIdx.x;
  if (i < n) p[i] = 0;
}

// ---------------- phase 1: partition edges into fixed-capacity coarse buckets -------
__global__ __launch_bounds__(512) void partition_kernel(
    const int* __restrict__ src, const int* __restrict__ dst, int E, int nB,
    int* __restrict__ bCur, unsigned* __restrict__ bucketData) {
  __shared__ int hist[391];
  __shared__ int gbase[391];
  const int t = threadIdx.x;
  const int b0 = blockIdx.x * 8192;

  for (int i = t; i < nB; i += 512) hist[i] = 0;
  __syncthreads();
#pragma unroll
  for (int i = 0; i < 16; ++i) {
    int e = b0 + i * 512 + t;
    if (e < E) atomicAdd(&hist[dst[e] >> 8], 1);
  }
  __syncthreads();
  for (int i = t; i < nB; i += 512) {
    int h = hist[i];
    gbase[i] = h ? (i * BCAP + atomicAdd(&bCur[i], h)) : 0;
    hist[i] = 0;
  }
  __syncthreads();
#pragma unroll
  for (int i = 0; i < 16; ++i) {
    int e = b0 + i * 512 + t;
    if (e < E) {
      int d = dst[e];
      int b = d >> 8;
      int r = atomicAdd(&hist[b], 1);
      bucketData[gbase[b] + r] = ((unsigned)(d & 255) << 17) | (unsigned)src[e];
    }
  }
}

// ---------------- phase 2: per-bucket node histogram + scan + scatter ----------------
__global__ __launch_bounds__(1024) void node_sort3(
    const unsigned* __restrict__ bucketData, const int* __restrict__ bCur,
    int N, int* __restrict__ sorted_src, int* __restrict__ rs, int* __restrict__ re) {
  extern __shared__ unsigned sdata[];          // LCAP entries
  __shared__ int hist[NPB];
  __shared__ int s[NPB];
  __shared__ int cur[NPB];
  const int b = blockIdx.x;
  const int t = threadIdx.x;
  const int start = b * BCAP;
  const int fill = bCur[b];
  if (t < NPB) hist[t] = 0;
  __syncthreads();
  // stage + histogram in one pass
  for (int i = t; i < fill; i += 1024) {
    unsigned d = bucketData[start + i];
    if (i < LCAP) sdata[i] = d;
    atomicAdd(&hist[d >> 17], 1);
  }
  __syncthreads();
  int v = 0;
  if (t < NPB) { v = hist[t]; s[t] = v; }
  __syncthreads();
  for (int off = 1; off < NPB; off <<= 1) {
    int y = (t < NPB && t >= off) ? s[t - off] : 0;
    __syncthreads();
    if (t < NPB) s[t] += y;
    __syncthreads();
  }
  if (t < NPB) {
    int excl = s[t] - v;
    const int node = b * NPB + t;
    if (node < N) {
      rs[node] = start + excl;
      re[node] = start + excl + v;
    }
    cur[t] = start + excl;
  }
  __syncthreads();
  for (int i = t; i < fill; i += 1024) {
    unsigned d = (i < LCAP) ? sdata[i] : bucketData[start + i];
    int p = atomicAdd(&cur[d >> 17], 1);
    sorted_src[p] = (int)(d & 0x1FFFF);
  }
}

// ---------------- weight pack: W[K][128] fp32 -> per-lane MFMA B-fragment order ------
__global__ void pack_w2(const float* __restrict__ Wl, const float* __restrict__ Wr,
                        _Float16* __restrict__ Bp) {
  const float* __restrict__ W = blockIdx.z ? Wr : Wl;
  const int tn = blockIdx.x;
  const int ks = blockIdx.y;
  const int KS = gridDim.y;
  const int lane = threadIdx.x;
  const int n = tn * 16 + (lane & 15);
  const int kb = ks * 32 + (lane >> 4) * 8;
  half8 v;
#pragma unroll
  for (int j = 0; j < 8; ++j) v[j] = (_Float16)W[(size_t)(kb + j) * HID + n];
  *(half8*)(Bp + (((size_t)(blockIdx.z * 8 + tn) * KS + ks) * 64 + lane) * 8) = v;
}

// ---------------- scorer linearization: ua=Wl2@wa, ub=Wl2@wb, va=Wr2@wa, vb=Wr2@wb ---
// uv layout: [0:128)=ua [128:256)=ub [256:384)=va [384:512)=vb [512]=b2.wa [513]=b2.wb
__global__ __launch_bounds__(128) void pack_uv(
    const float* __restrict__ Wl2, const float* __restrict__ Wr2,
    const float* __restrict__ bl2, const float* __restrict__ Wlin,
    float* __restrict__ uv) {
  const int i = threadIdx.x;   // 0..127
  float ua = 0.f, ub = 0.f, va = 0.f, vb = 0.f;
  for (int o = 0; o < 128; ++o) {
    float wa = Wlin[o], wb = Wlin[128 + o];
    float l = Wl2[i * 128 + o], r = Wr2[i * 128 + o];
    ua += l * wa; ub += l * wb;
    va += r * wa; vb += r * wb;
  }
  uv[i] = ua; uv[128 + i] = ub; uv[256 + i] = va; uv[384 + i] = vb;
  if (i == 0) {
    float ca = 0.f, cb = 0.f;
    for (int o = 0; o < 128; ++o) {
      ca += bl2[o] * Wlin[o];
      cb += bl2[o] * Wlin[128 + o];
    }
    uv[512] = ca; uv[513] = cb;
  }
}

// ---------------- cvt helper: pack two fp32 -> fp16x2 (RTZ), as half2t --------------
__device__ inline half2t cvt_pk(float a, float b) {
  fp16x2 r = __builtin_amdgcn_cvt_pkrtz(a, b);
  union { fp16x2 f; half2t h; } c;
  c.f = r;
  return c.h;
}

// ---------------- GEMM (fp32 A), layer 1: y8[M x 128] fp8 e4m3 + z1[M x 128] fp16 ----
__global__ __launch_bounds__(512) void gemm_f32a(
    const float* __restrict__ A, int M,
    const _Float16* __restrict__ Bp,
    unsigned char* __restrict__ y8, _Float16* __restrict__ z1) {
  __shared__ float As[128 * 32];   // (row*8 + cg_phys)*4 floats, cg_phys = cg ^ (row&7)

  const int K = IN_DIM, KS = IN_DIM / 32;
  const int tid = threadIdx.x;
  const int lane = tid & 63;
  const int wid = tid >> 6;
  const int quad = lane >> 4;
  const int lm = lane & 15;
  const int row0 = (wid & 1) * 64;
  const int ct0 = (wid >> 1) * 4;
  const int blockRow = blockIdx.x * 128;

  const int srow = lane >> 3;
  const int scol = ((lane & 7) ^ (srow & 7)) * 4;
  const int grow0 = min(blockRow + wid * 16 + srow, M - 1);
  const int grow1 = min(blockRow + wid * 16 + 8 + srow, M - 1);

  floatx4 acc[16];
#pragma unroll
  for (int i = 0; i < 16; ++i) {
    acc[i][0] = 0.f; acc[i][1] = 0.f; acc[i][2] = 0.f; acc[i][3] = 0.f;
  }

  for (int ks = 0; ks < KS; ++ks) {
    const int k0 = ks * 32;
    __syncthreads();
    __builtin_amdgcn_global_load_lds(
        (const AS1 void*)(A + (size_t)grow0 * K + k0 + scol),
        (AS3 void*)(As + (wid * 16) * 32), 16, 0, 0);
    __builtin_amdgcn_global_load_lds(
        (const AS1 void*)(A + (size_t)grow1 * K + k0 + scol),
        (AS3 void*)(As + (wid * 16 + 8) * 32), 16, 0, 0);

    half8 bf[4];
#pragma unroll
    for (int ct = 0; ct < 4; ++ct)
      bf[ct] = *(const half8*)(Bp + (((size_t)(ct0 + ct) * KS + ks) * 64 + lane) * 8);

    __syncthreads();

    half8 af[4];
#pragma unroll
    for (int rt = 0; rt < 4; ++rt) {
      const int row = row0 + rt * 16 + lm;
      const int sw = row & 7;
      const floatx4 fA = *(const floatx4*)&As[(row * 8 + ((quad * 2) ^ sw)) * 4];
      const floatx4 fB = *(const floatx4*)&As[(row * 8 + ((quad * 2 + 1) ^ sw)) * 4];
      half2t h01 = cvt_pk(fA[0], fA[1]);
      half2t h23 = cvt_pk(fA[2], fA[3]);
      half2t h45 = cvt_pk(fB[0], fB[1]);
      half2t h67 = cvt_pk(fB[2], fB[3]);
      half8 a;
      a[0] = h01[0]; a[1] = h01[1]; a[2] = h23[0]; a[3] = h23[1];
      a[4] = h45[0]; a[5] = h45[1]; a[6] = h67[0]; a[7] = h67[1];
      af[rt] = a;
    }
#pragma unroll
    for (int rt = 0; rt < 4; ++rt)
#pragma unroll
      for (int ct = 0; ct < 4; ++ct)
        acc[rt * 4 + ct] =
            __builtin_amdgcn_mfma_f32_16x16x32_f16(af[rt], bf[ct], acc[rt * 4 + ct], 0, 0, 0);
  }

#pragma unroll
  for (int rt = 0; rt < 4; ++rt) {
#pragma unroll
    for (int r = 0; r < 4; ++r) {
      const int gm = blockRow + row0 + rt * 16 + quad * 4 + r;
      if (gm < M) {
#pragma unroll
        for (int ct = 0; ct < 4; ++ct) {
          const int tn = ct0 + ct;
          const float v = acc[rt * 4 + ct][r];
          if (tn < 8) {
            int p = __builtin_amdgcn_cvt_pk_fp8_f32(v, v, 0, false);
            y8[(size_t)gm * 128 + tn * 16 + lm] = (unsigned char)(p & 0xFF);
          } else {
            z1[(size_t)gm * 128 + (tn - 8) * 16 + lm] = (_Float16)v;
          }
        }
      }
    }
  }
}

// ---------------- helpers ----------------
__device__ inline float2 upk(unsigned u) {
  union { unsigned v; _Float16 h[2]; } c; c.v = u;
  return make_float2((float)c.h[0], (float)c.h[1]);
}

// ---------------- fp8 gather accumulator: 8 fp8 -> 4x float2 pk-adds ----------------
struct f32acc8 { floatx2 a, b, c, d; };
__device__ inline void f8acc(f32acc8& A, uint2 v) {
  A.a += __builtin_amdgcn_cvt_pk_f32_fp8(v.x, false);
  A.b += __builtin_amdgcn_cvt_pk_f32_fp8(v.x, true);
  A.c += __builtin_amdgcn_cvt_pk_f32_fp8(v.y, false);
  A.d += __builtin_amdgcn_cvt_pk_f32_fp8(v.y, true);
}
__device__ inline void f8merge(f32acc8& A, const f32acc8& B) {
  A.a += B.a; A.b += B.b; A.c += B.c; A.d += B.d;
}

// ---------------- layer-1 gather (fp8 rows, 128B): 16 col-lanes x 4 edge slots -------
__device__ inline f32acc8 gather_rows8(const unsigned char* __restrict__ y8,
                                       const int* __restrict__ sorted_src,
                                       int start, int end, int cl, int slot) {
  f32acc8 A0; A0.a = 0.f; A0.b = 0.f; A0.c = 0.f; A0.d = 0.f;
  f32acc8 A1 = A0;
  int k = start + slot;
  for (; k + 12 < end; k += 16) {
    int s0 = sorted_src[k];
    int s1 = sorted_src[k + 4];
    int s2 = sorted_src[k + 8];
    int s3 = sorted_src[k + 12];
    uint2 v0 = *(const uint2*)(y8 + (size_t)s0 * 128 + cl * 8);
    uint2 v1 = *(const uint2*)(y8 + (size_t)s1 * 128 + cl * 8);
    uint2 v2 = *(const uint2*)(y8 + (size_t)s2 * 128 + cl * 8);
    uint2 v3 = *(const uint2*)(y8 + (size_t)s3 * 128 + cl * 8);
    f8acc(A0, v0);
    f8acc(A1, v1);
    f8acc(A0, v2);
    f8acc(A1, v3);
  }
  if (k + 4 < end) {   // 2-deep tail
    int s0 = sorted_src[k];
    int s1 = sorted_src[k + 4];
    uint2 v0 = *(const uint2*)(y8 + (size_t)s0 * 128 + cl * 8);
    uint2 v1 = *(const uint2*)(y8 + (size_t)s1 * 128 + cl * 8);
    f8acc(A0, v0);
    f8acc(A1, v1);
    k += 8;
  }
  if (k < end) {
    uint2 v = *(const uint2*)(y8 + (size_t)sorted_src[k] * 128 + cl * 8);
    f8acc(A0, v);
  }
  f8merge(A0, A1);
#pragma unroll
  for (int off = 16; off < 64; off <<= 1) {
    f32acc8 o;
    o.a[0] = __shfl_xor(A0.a[0], off, 64); o.a[1] = __shfl_xor(A0.a[1], off, 64);
    o.b[0] = __shfl_xor(A0.b[0], off, 64); o.b[1] = __shfl_xor(A0.b[1], off, 64);
    o.c[0] = __shfl_xor(A0.c[0], off, 64); o.c[1] = __shfl_xor(A0.c[1], off, 64);
    o.d[0] = __shfl_xor(A0.d[0], off, 64); o.d[1] = __shfl_xor(A0.d[1], off, 64);
    f8merge(A0, o);
  }
  return A0;
}

// ---------------- layer-1 aggregate + ReLU + fused scorer-basis dots ----------------
// h1 lives only in registers. Writes t[n] = (h1.ua, h1.ub) and
// r[n] = (h1.va + b2.wa, h1.vb + b2.wb). No h1 materialization.
__global__ __launch_bounds__(256) void agg_relu8_dot(
    const unsigned char* __restrict__ y8, const unsigned* __restrict__ z1u,
    const int* __restrict__ sorted_src,
    const int* __restrict__ rs, const int* __restrict__ re,
    const float* __restrict__ bias, const float* __restrict__ uv,
    float2* __restrict__ t, float2* __restrict__ r, int N) {
  const int w = threadIdx.x >> 6;
  const int lane = threadIdx.x & 63;
  const int cl = lane & 15;
  const int slot = lane >> 4;
  const int node = blockIdx.x * 4 + w;
  if (node >= N) return;
  const int start = rs[node];
  const int end = re[node];
  f32acc8 A = gather_rows8(y8, sorted_src, start, end, cl, slot);
  if (slot == 0) {
    const int deg = end - start;
    const float inv = 1.f / (float)max(deg, 1);
    uint4 z4 = *(const uint4*)(z1u + (size_t)node * 64 + cl * 4);
    const unsigned zv[4] = {z4.x, z4.y, z4.z, z4.w};
    const floatx2 av[4] = {A.a, A.b, A.c, A.d};
    float hv[8];
#pragma unroll
    for (int q = 0; q < 4; ++q) {
      const int c = cl * 8 + q * 2;
      float2 z = upk(zv[q]);
      hv[2 * q]     = fmaxf(av[q][0] * inv + bias[c] + z.x, 0.f);
      hv[2 * q + 1] = fmaxf(av[q][1] * inv + bias[c + 1] + z.y, 0.f);
    }
    float ta = 0.f, tb = 0.f, ra = 0.f, rb = 0.f;
#pragma unroll
    for (int j = 0; j < 8; ++j) {
      const int c = cl * 8 + j;
      ta += hv[j] * uv[c];
      tb += hv[j] * uv[128 + c];
      ra += hv[j] * uv[256 + c];
      rb += hv[j] * uv[384 + c];
    }
    // reduce across the 16 cl lanes (lanes 0-15, xor bits 0-3)
#pragma unroll
    for (int off = 1; off < 16; off <<= 1) {
      ta += __shfl_xor(ta, off, 64);
      tb += __shfl_xor(tb, off, 64);
      ra += __shfl_xor(ra, off, 64);
      rb += __shfl_xor(rb, off, 64);
    }
    if (cl == 0) {
      t[node] = make_float2(ta, tb);
      r[node] = make_float2(ra + uv[512], rb + uv[513]);
    }
  }
}

// ---------------- layer-2 aggregate: gather the 800KB L2-resident t table -----------
// lane = ns*16 + es: 4 node-slots x 16 edge-slots. 8 B per edge.
__global__ __launch_bounds__(256) void agg_t(
    const float2* __restrict__ t, const int* __restrict__ sorted_src,
    const int* __restrict__ rs, const int* __restrict__ re,
    const float2* __restrict__ r,
    float* __restrict__ sa, float* __restrict__ sb, int N) {
  const int w = threadIdx.x >> 6;
  const int lane = threadIdx.x & 63;
  const int es = lane & 15;
  const int ns = lane >> 4;
  const int node = blockIdx.x * 16 + w * 4 + ns;
  if (node >= N) return;
  const int start = rs[node];
  const int end = re[node];
  float a = 0.f, b = 0.f;
  for (int k = start + es; k < end; k += 16) {
    float2 v = t[sorted_src[k]];
    a += v.x;
    b += v.y;
  }
  // reduce over the 16 es slots (xor bits 0-3)
#pragma unroll
  for (int off = 1; off < 16; off <<= 1) {
    a += __shfl_xor(a, off, 64);
    b += __shfl_xor(b, off, 64);
  }
  if (es == 0) {
    const int deg = end - start;
    const float inv = 1.f / (float)max(deg, 1);
    float2 rr = r[node];
    sa[node] = a * inv + rr.x;
    sb[node] = b * inv + rr.y;
  }
}

// ---------------- edge scoring (both pos and neg in one launch) ----------------
__global__ void score2(const int* __restrict__ pos, const int* __restrict__ neg,
                       int Ep, int En,
                       const float* __restrict__ sa, const float* __restrict__ sb,
                       const float* __restrict__ blin, float* __restrict__ out) {
  int e = blockIdx.x * 256 + threadIdx.x;
  if (e < Ep) {
    out[e] = sa[pos[e]] + sb[pos[Ep + e]] + blin[0];
  } else if (e < Ep + En) {
    int i = e - Ep;
    out[Ep + i] = sa[neg[i]] + sb[neg[En + i]] + blin[0];
  }
}

extern "C" void kernel_launch(void* const* d_in, const int* in_sizes, int n_in,
                              void* d_out, int out_size, void* d_ws, size_t ws_size,
                              hipStream_t stream) {
  (void)n_in; (void)out_size; (void)ws_size;
  const float* x    = (const float*)d_in[0];
  const int*   ei   = (const int*)d_in[1];
  const int*   pos  = (const int*)d_in[2];
  const int*   neg  = (const int*)d_in[3];
  const float* Wl1  = (const float*)d_in[4];
  const float* bl1  = (const float*)d_in[5];
  const float* Wr1  = (const float*)d_in[6];
  const float* Wl2  = (const float*)d_in[7];
  const float* bl2  = (const float*)d_in[8];
  const float* Wr2  = (const float*)d_in[9];
  const float* Wlin = (const float*)d_in[10];
  const float* blin = (const float*)d_in[11];

  const int N  = in_sizes[0] / IN_DIM;  // 100000
  const int E  = in_sizes[1] / 2;       // 3200000
  const int Ep = in_sizes[2] / 2;       // 500000
  const int En = in_sizes[3] / 2;       // 500000
  const int* e_src = ei;
  const int* e_dst = ei + E;

  char* ws = (char*)d_ws;
  size_t off = 0;
  auto carve = [&](size_t bytes) -> char* {
    char* p = ws + off;
    off += (bytes + 255) & ~(size_t)255;
    return p;
  };
  const int nB = (N + NPB - 1) / NPB;   // 391 buckets
  const int KS1 = IN_DIM / 32;          // 12

  int*           rs     = (int*)carve((size_t)N * 4);
  int*           re     = (int*)carve((size_t)N * 4);
  int*           bCur   = (int*)carve(512 * 4);
  unsigned*      bData  = (unsigned*)carve((size_t)nB * BCAP * 4);
  int*           sorted = (int*)carve((size_t)nB * BCAP * 4);
  float*         sa     = (float*)carve((size_t)N * 4);
  float*         sb     = (float*)carve((size_t)N * 4);
  _Float16*      Bp1    = (_Float16*)carve((size_t)16 * KS1 * 64 * 8 * 2);
  float*         uv     = (float*)carve(516 * 4);
  float2*        tbuf   = (float2*)carve((size_t)N * 8);
  float2*        rbuf   = (float2*)carve((size_t)N * 8);
  unsigned char* y8     = (unsigned char*)carve((size_t)N * 128);
  _Float16*      z1     = (_Float16*)carve((size_t)N * 128 * 2);

  const int gemmBlocks = (N + 127) / 128;
  const int partBlocks = (E + 8191) / 8192;  // 391

  // CSR build
  hipLaunchKernelGGL(zero_i32, dim3(2), dim3(256), 0, stream, bCur, 512);
  hipLaunchKernelGGL(partition_kernel, dim3(partBlocks), dim3(512), 0, stream,
                     e_src, e_dst, E, nB, bCur, bData);
  hipLaunchKernelGGL(node_sort3, dim3(nB), dim3(1024), LCAP * 4, stream,
                     bData, bCur, N, sorted, rs, re);

  // weight packing (layer 1) + scorer-basis vectors (layer 2 linearization)
  hipLaunchKernelGGL(pack_w2, dim3(8, KS1, 2), dim3(64), 0, stream, Wl1, Wr1, Bp1);
  hipLaunchKernelGGL(pack_uv, dim3(1), dim3(128), 0, stream, Wl2, Wr2, bl2, Wlin, uv);

  // layer 1 (y in fp8 for the gather, z in fp16)
  hipLaunchKernelGGL(gemm_f32a, dim3(gemmBlocks), dim3(512), 0, stream,
                     x, N, Bp1, y8, z1);
  // layer-1 aggregate + ReLU + scorer-basis dots (h1 stays in registers)
  hipLaunchKernelGGL(agg_relu8_dot, dim3((N + 3) / 4), dim3(256), 0, stream,
                     y8, (const unsigned*)z1, sorted, rs, re, bl1, uv, tbuf, rbuf, N);
  // layer-2 aggregate over the scalar t table (L2-resident)
  hipLaunchKernelGGL(agg_t, dim3((N + 15) / 16), dim3(256), 0, stream,
                     tbuf, sorted, rs, re, rbuf, sa, sb, N);

  // scoring (single launch)
  float* out = (float*)d_out;
  hipLaunchKernelGGL(score2, dim3((Ep + En + 255) / 256), dim3(256), 0, stream,
                     pos, neg, Ep, En, sa, sb, blin, out);
}